// Round 18
// baseline (34.103 us; speedup 1.0000x reference)
//
#include <hip/hip_runtime.h>
#include <math.h>

#define DD 8
#define MM 7
#define MOO 9
#define NPTS 100
#define EPSF 1e-5f

#define THREADS 1024
#define ITERS 8           // uint4 code loads per thread; THREADS*4*ITERS == 32768
#define ROWS 8            // batch rows per block
#define CAP 256           // candidate buffer capacity per row
#define LSLACK 6          // log-threshold slack, units of 1/128 log2

typedef unsigned uint32x4 __attribute__((ext_vector_type(4)));

// ---------------- pack: antecedents -> entry-index word ---------------------
// w & 0xFFFF = entry index into quad table 0 (0..4095)
// w >> 16    = entry index into quad table 1 (4096..8191, base pre-added)
__global__ __launch_bounds__(256) void pack_kernel(const int* __restrict__ ant,
                                                   unsigned* __restrict__ g_off,
                                                   int R) {
    int r = blockIdx.x * 256 + threadIdx.x;
    if (r < R) {
        const int4* a = reinterpret_cast<const int4*>(ant) + (size_t)r * 2;
        int4 lo = a[0], hi = a[1];
        int v[8] = {lo.x, lo.y, lo.z, lo.w, hi.x, hi.y, hi.z, hi.w};
        unsigned code = 0u;
        #pragma unroll
        for (int i = 0; i < 8; ++i) {
            int c = v[i];
            c = (c < 0) ? 7 : (c > MM - 1 ? MM - 1 : c);   // -1 -> wildcard slot 7
            code |= (unsigned)c << (3 * i);
        }
        g_off[r] = (code & 4095u) | (((code >> 12) + 4096u) << 16);
    }
}

// =================== fused kernel: 8 rows/block, scan + select ==============
// R17 bugfix: log scale 256 -> 128. R17's int16 sums reached -34030 and
// WRAPPED (quad >= EPS^4 = 1e-20 -> 256*log2 = -17015 each). At scale 128:
// quad l in [-8506,-1], sum in [-17012,-2] -- fits int16 with 2x headroom.
// l = floor(128*log2(q)) - 1 is one-sided (l <= 128*log2 exact), sum deficit
// <= 4 LSB -> LSLACK=6. Phase 6 recomputes EXACT f32 f and selects by exact
// (val desc, idx asc) -> bit-identical output.
__global__ __launch_bounds__(THREADS, 4) void anfis_fused8(
    const float* __restrict__ x,
    const unsigned* __restrict__ stream_off,
    const int* __restrict__ consequents,
    const float* __restrict__ in_centers,   // [D][M]
    const float* __restrict__ in_widths,    // [D][M]
    const float* __restrict__ out_centers,  // [MO]
    const float* __restrict__ out_widths,   // [MO]
    float* __restrict__ out)
{
    __shared__ uint4 quads[8192];        // 128 KB; aliased after phase 3:
                                         //   bytes [0,16K):  ushort wl[8192]
                                         //   bytes [16K,24K): float cvals[8][256]
                                         //   bytes [24K,32K): int   cidx[8][256]
    __shared__ float mu[ROWS][64];       // 2 KB
    __shared__ float pairs_t[2048];      // 8 KB exact f32 pairs, [entry][row]
    __shared__ uint4 smaxpk[THREADS];    // 16 KB packed int16 thread maxes
    __shared__ float s0s[MOO], s1s[MOO];
    __shared__ int   sTi[ROWS];          // threshold, int log domain
    __shared__ float sTf[ROWS];          // exact-domain rule filter threshold
    __shared__ int   scnt[ROWS];
    __shared__ int   wlcnt;
    __shared__ float wv[ROWS][8];
    __shared__ int   wc[ROWS][8];

    const int tid = threadIdx.x;
    const int b0  = blockIdx.x * ROWS;

    unsigned short* wl = (unsigned short*)quads;          // 16 KB
    float* cvals = (float*)(quads + 1024);                // 8 KB  @16K
    int*   cidx  = (int*)(quads + 1536);                  // 8 KB  @24K

    // --- phase 0: membership tables (8 rows) + init ---
    if (tid < 512) {
        int row = tid >> 6, d = (tid >> 3) & 7, c = tid & 7;
        float v = 1.0f;
        if (c < MM) {
            float z = (x[(b0 + row) * DD + d] - in_centers[d * MM + c]) / in_widths[d * MM + c];
            v = expf(-0.5f * z * z);
            v = fminf(v, 1.0f);
            v = fmaxf(v, EPSF);
        }
        mu[row][(d << 3) + c] = v;
    } else if (tid >= 544 && tid < 544 + ROWS) {
        scnt[tid - 544] = 0;
    } else if (tid == 560) {
        wlcnt = 0;
    }
    __syncthreads();

    // --- phase 1: exact pair products, transposed [entry][row] ---
    #pragma unroll
    for (int i = 0; i < 2; ++i) {
        int k = tid + i * THREADS;          // k = e*8 + row
        int e = k >> 3, row = k & 7;
        int p = e >> 6, q = e & 63;
        pairs_t[k] = mu[row][(2 * p) * 8 + (q & 7)] * mu[row][(2 * p + 1) * 8 + (q >> 3)];
    }
    __syncthreads();

    // --- phase 2: quad tables, int16 log (scale 128) x 8 rows per entry ---
    // l = floor(128*log2(a*b)) - 1  (one-sided: l <= 128*log2(exact))
    #pragma unroll
    for (int h = 0; h < 2; ++h) {
        float a8[ROWS];
        const int ia = h * 128 + (tid & 63);
        #pragma unroll
        for (int r = 0; r < ROWS; ++r) a8[r] = pairs_t[ia * 8 + r];
        #pragma unroll
        for (int ii = 0; ii < 4; ++ii) {
            int k = tid + (h * 4 + ii) * THREADS;
            int ib = h * 128 + 64 + ((((tid >> 6) + 16 * ii)) & 63);
            int l[ROWS];
            #pragma unroll
            for (int r = 0; r < ROWS; ++r) {
                float q = a8[r] * pairs_t[ib * 8 + r];
                l[r] = (int)floorf(__log2f(q) * 128.0f) - 1;
            }
            quads[k] = make_uint4(((unsigned)l[1] << 16) | ((unsigned)l[0] & 0xFFFFu),
                                  ((unsigned)l[3] << 16) | ((unsigned)l[2] & 0xFFFFu),
                                  ((unsigned)l[5] << 16) | ((unsigned)l[4] & 0xFFFFu),
                                  ((unsigned)l[7] << 16) | ((unsigned)l[6] & 0xFFFFu));
        }
    }
    __syncthreads();

    // --- phase 3: pipelined scan; packed i16 add/max (2 rows per inst) ---
    const uint4* pk4 = reinterpret_cast<const uint4*>(stream_off);
    const unsigned qbase = (unsigned)(uintptr_t)&quads[0];
    unsigned m01 = 0x80008000u, m23 = 0x80008000u;
    unsigned m45 = 0x80008000u, m67 = 0x80008000u;
    {
        uint32x4 a0, a1, a2, a3, b0, b1, b2, b3;   // buffer A (even batches)
        uint32x4 c0, c1, c2, c3, d0, d1, d2, d3;   // buffer B (odd batches)

        #define ISSUE(J, RA0, RB0, RA1, RB1, RA2, RB2, RA3, RB3)                   \
        {                                                                          \
            uint4 cd = pk4[(J) * THREADS + tid];                                   \
            asm volatile("ds_read_b128 %0, %1" : "=v"(RA0) : "v"(qbase + ((cd.x & 0xFFFFu) << 4))); \
            asm volatile("ds_read_b128 %0, %1" : "=v"(RB0) : "v"(qbase + ((cd.x >> 16) << 4)));     \
            asm volatile("ds_read_b128 %0, %1" : "=v"(RA1) : "v"(qbase + ((cd.y & 0xFFFFu) << 4))); \
            asm volatile("ds_read_b128 %0, %1" : "=v"(RB1) : "v"(qbase + ((cd.y >> 16) << 4)));     \
            asm volatile("ds_read_b128 %0, %1" : "=v"(RA2) : "v"(qbase + ((cd.z & 0xFFFFu) << 4))); \
            asm volatile("ds_read_b128 %0, %1" : "=v"(RB2) : "v"(qbase + ((cd.z >> 16) << 4)));     \
            asm volatile("ds_read_b128 %0, %1" : "=v"(RA3) : "v"(qbase + ((cd.w & 0xFFFFu) << 4))); \
            asm volatile("ds_read_b128 %0, %1" : "=v"(RB3) : "v"(qbase + ((cd.w >> 16) << 4)));     \
        }
        #define RULEPK(A, B)                                                       \
        {                                                                          \
            unsigned s0_, s1_, s2_, s3_;                                           \
            asm("v_pk_add_i16 %0, %1, %2" : "=v"(s0_) : "v"((A)[0]), "v"((B)[0])); \
            asm("v_pk_add_i16 %0, %1, %2" : "=v"(s1_) : "v"((A)[1]), "v"((B)[1])); \
            asm("v_pk_add_i16 %0, %1, %2" : "=v"(s2_) : "v"((A)[2]), "v"((B)[2])); \
            asm("v_pk_add_i16 %0, %1, %2" : "=v"(s3_) : "v"((A)[3]), "v"((B)[3])); \
            asm("v_pk_max_i16 %0, %1, %2" : "=v"(m01) : "v"(m01), "v"(s0_));       \
            asm("v_pk_max_i16 %0, %1, %2" : "=v"(m23) : "v"(m23), "v"(s1_));       \
            asm("v_pk_max_i16 %0, %1, %2" : "=v"(m45) : "v"(m45), "v"(s2_));       \
            asm("v_pk_max_i16 %0, %1, %2" : "=v"(m67) : "v"(m67), "v"(s3_));       \
        }
        #define WAIT8()                                                            \
            __builtin_amdgcn_sched_barrier(0);                                     \
            asm volatile("s_waitcnt lgkmcnt(8)" ::: "memory");                     \
            __builtin_amdgcn_sched_barrier(0);
        #define WAIT0()                                                            \
            __builtin_amdgcn_sched_barrier(0);                                     \
            asm volatile("s_waitcnt lgkmcnt(0)" ::: "memory");                     \
            __builtin_amdgcn_sched_barrier(0);
        #define CONA  RULEPK(a0, b0) RULEPK(a1, b1) RULEPK(a2, b2) RULEPK(a3, b3)
        #define CONB  RULEPK(c0, d0) RULEPK(c1, d1) RULEPK(c2, d2) RULEPK(c3, d3)

        ISSUE(0, a0, b0, a1, b1, a2, b2, a3, b3)
        ISSUE(1, c0, d0, c1, d1, c2, d2, c3, d3)  WAIT8()  CONA
        ISSUE(2, a0, b0, a1, b1, a2, b2, a3, b3)  WAIT8()  CONB
        ISSUE(3, c0, d0, c1, d1, c2, d2, c3, d3)  WAIT8()  CONA
        ISSUE(4, a0, b0, a1, b1, a2, b2, a3, b3)  WAIT8()  CONB
        ISSUE(5, c0, d0, c1, d1, c2, d2, c3, d3)  WAIT8()  CONA
        ISSUE(6, a0, b0, a1, b1, a2, b2, a3, b3)  WAIT8()  CONB
        ISSUE(7, c0, d0, c1, d1, c2, d2, c3, d3)  WAIT8()  CONA
        WAIT0()  CONB

        #undef ISSUE
        #undef RULEPK
        #undef WAIT8
        #undef WAIT0
        #undef CONA
        #undef CONB
    }
    smaxpk[tid] = make_uint4(m01, m23, m45, m67);
    __syncthreads();          // quads DEAD from here on

    // --- phase 4: waves 0-7 extract int thresholds; wave 8 defuzz consts ---
    if (tid < 512) {
        int row = tid >> 6, lane = tid & 63;
        int mm[16];
        #pragma unroll
        for (int k = 0; k < 16; ++k) {
            uint4 e = smaxpk[lane + 64 * k];
            unsigned word = (row & 4) ? ((row & 2) ? e.w : e.z)
                                      : ((row & 2) ? e.y : e.x);
            mm[k] = (row & 1) ? ((int)word >> 16) : ((int)(word << 16) >> 16);
        }
        int thr = -0x7FFFFFFF;
        #pragma unroll
        for (int round = 0; round < 8; ++round) {
            int lm = mm[0];
            #pragma unroll
            for (int k = 1; k < 16; ++k) lm = max(lm, mm[k]);
            int wm = lm;
            #pragma unroll
            for (int off = 32; off >= 1; off >>= 1)
                wm = max(wm, __shfl_xor(wm, off, 64));
            unsigned long long bal = __ballot(lm == wm);
            int first = (int)__ffsll(bal) - 1;
            if (lane == first) {                // remove exactly one instance
                bool done = false;
                #pragma unroll
                for (int k = 0; k < 16; ++k) {
                    bool rm = (!done) && (mm[k] == wm);
                    mm[k] = rm ? -0x7FFFFFFF : mm[k];
                    done = done || rm;
                }
            }
            thr = wm;
        }
        if (lane == 0) {
            sTi[row] = thr;
            sTf[row] = exp2f((float)thr * (1.0f / 128.0f)) * 0.9999f;
        }
    } else if (tid < 512 + MOO) {
        int mo = tid - 512;
        float oc = out_centers[mo], ow = out_widths[mo];
        float s0 = 0.0f, s1 = 0.0f;
        for (int p = 0; p < NPTS; ++p) {
            float u = (float)p * (1.0f / 99.0f);
            float z = (u - oc) / ow;
            float e = expf(-0.5f * z * z);
            s0 += e;
            s1 += u * e;
        }
        s0s[mo] = s0;
        s1s[mo] = s1;
    }
    __syncthreads();

    // --- phase 5: wave-aggregated worklist append (1 atomic/wave/row) ---
    {
        const int lane = tid & 63;
        int myl[8];
        myl[0] = (int)(m01 << 16) >> 16;  myl[1] = (int)m01 >> 16;
        myl[2] = (int)(m23 << 16) >> 16;  myl[3] = (int)m23 >> 16;
        myl[4] = (int)(m45 << 16) >> 16;  myl[5] = (int)m45 >> 16;
        myl[6] = (int)(m67 << 16) >> 16;  myl[7] = (int)m67 >> 16;
        #pragma unroll
        for (int row = 0; row < ROWS; ++row) {
            bool q = myl[row] >= sTi[row] - LSLACK;
            unsigned long long bal = __ballot(q);
            if (bal) {
                int lead = (int)__ffsll(bal) - 1;
                int base = 0;
                if (lane == lead) base = atomicAdd(&wlcnt, (int)__popcll(bal));
                base = __shfl(base, lead, 64);
                if (q) {
                    int off = (int)__popcll(bal & ((1ull << lane) - 1ull));
                    wl[base + off] = (unsigned short)((row << 10) | tid);
                }
            }
        }
    }
    __syncthreads();

    // --- phase 6: half-wave per item; EXACT f32 recompute vs sTf ---
    {
        const int hl = tid & 31;                   // rule slot within item
        const int j = hl >> 2, s = hl & 3;
        const int n = wlcnt;
        for (int i = (tid >> 5); i < n; i += 32) {
            int it  = wl[i];
            int row = it >> 10;
            int t   = it & 1023;
            int flat = (j * THREADS + t) * 4 + s;
            unsigned w = stream_off[flat];
            unsigned lo12 = w & 0xFFFFu;
            unsigned hi12 = (w >> 16) - 4096u;
            float f = (pairs_t[(lo12 & 63u) * 8 + row] * pairs_t[(64 + (lo12 >> 6)) * 8 + row])
                    * (pairs_t[(128 + (hi12 & 63u)) * 8 + row] * pairs_t[(192 + (hi12 >> 6)) * 8 + row]);
            if (f >= sTf[row]) {
                int pos = atomicAdd(&scnt[row], 1);
                if (pos < CAP) {
                    cvals[row * CAP + pos] = f;
                    cidx[row * CAP + pos]  = flat;
                }
            }
        }
    }
    __syncthreads();

    // --- phase 7: exact rank selection per row (val desc, orig idx asc) ---
    if (tid < 512) {
        int row = tid >> 6, lane = tid & 63;
        int n = scnt[row] < CAP ? scnt[row] : CAP;
        for (int c = lane; c < n; c += 64) {
            float v  = cvals[row * CAP + c];
            int   id = cidx[row * CAP + c];
            int rk = 0;
            for (int mI = 0; mI < n; ++mI) {
                float vm = cvals[row * CAP + mI];
                int   im = cidx[row * CAP + mI];
                rk += ((vm > v) || (vm == v && im < id)) ? 1 : 0;
            }
            if (rk < 8) {
                wv[row][rk] = v;
                wc[row][rk] = consequents[id];
            }
        }
    }
    __syncthreads();

    // --- phase 8: defuzzify ---
    if (tid < ROWS) {
        int row = tid;
        float num = 0.0f, den = 0.0f;
        #pragma unroll
        for (int k = 0; k < 8; ++k) {
            num += wv[row][k] * s1s[wc[row][k]];
            den += wv[row][k] * s0s[wc[row][k]];
        }
        out[b0 + row] = num / (den + EPSF);
    }
}

// ---------------- generic fallback (round-1 kernel, inline pack) ------------
__global__ __launch_bounds__(256) void anfis_kernel(
    const float* __restrict__ x,
    const int* __restrict__ ant,
    const int* __restrict__ consequents,
    const float* __restrict__ in_centers,
    const float* __restrict__ in_widths,
    const float* __restrict__ out_centers,
    const float* __restrict__ out_widths,
    float* __restrict__ out,
    int R)
{
    __shared__ float mu[64];
    __shared__ float pairs[256];
    __shared__ float s0s[MOO], s1s[MOO];
    __shared__ float svals[256][9];
    __shared__ int   sidx[256][9];

    const int tid = threadIdx.x;
    const int b   = blockIdx.x;

    if (tid < 64) {
        int d = tid >> 3, c = tid & 7;
        float v = 1.0f;
        if (c < MM) {
            float z = (x[b * DD + d] - in_centers[d * MM + c]) / in_widths[d * MM + c];
            v = expf(-0.5f * z * z);
            v = fminf(v, 1.0f);
            v = fmaxf(v, EPSF);
        }
        mu[tid] = v;
    } else if (tid < 64 + MOO) {
        int mo = tid - 64;
        float oc = out_centers[mo], ow = out_widths[mo];
        float s0 = 0.0f, s1 = 0.0f;
        for (int p = 0; p < NPTS; ++p) {
            float u = (float)p * (1.0f / 99.0f);
            float z = (u - oc) / ow;
            float e = expf(-0.5f * z * z);
            s0 += e;
            s1 += u * e;
        }
        s0s[mo] = s0;
        s1s[mo] = s1;
    }
    __syncthreads();

    {
        int p = tid >> 6, q = tid & 63;
        pairs[tid] = mu[(2 * p) * 8 + (q & 7)] * mu[(2 * p + 1) * 8 + (q >> 3)];
    }
    __syncthreads();

    float vals[8];
    int   idxs[8];
    #pragma unroll
    for (int k = 0; k < 8; ++k) { vals[k] = -1.0f; idxs[k] = 0x7fffffff; }

    for (int r = tid; r < R; r += 256) {
        const int4* a = reinterpret_cast<const int4*>(ant) + (size_t)r * 2;
        int4 lo = a[0], hi = a[1];
        int v[8] = {lo.x, lo.y, lo.z, lo.w, hi.x, hi.y, hi.z, hi.w};
        unsigned code = 0u;
        #pragma unroll
        for (int i = 0; i < 8; ++i) {
            int c = v[i];
            c = (c < 0) ? 7 : (c > MM - 1 ? MM - 1 : c);
            code |= (unsigned)c << (3 * i);
        }
        float f = pairs[code & 63]
                * pairs[64  + ((code >> 6)  & 63)]
                * pairs[128 + ((code >> 12) & 63)]
                * pairs[192 + ((code >> 18) & 63)];
        if (f > vals[7]) {
            float nv = f; int ni = r;
            #pragma unroll
            for (int k = 0; k < 8; ++k) {
                bool take = nv > vals[k];
                float cv = vals[k]; int ci = idxs[k];
                vals[k] = take ? nv : cv;
                idxs[k] = take ? ni : ci;
                nv = take ? cv : nv;
                ni = take ? ci : ni;
            }
        }
    }

    #pragma unroll
    for (int k = 0; k < 8; ++k) { svals[tid][k] = vals[k]; sidx[tid][k] = idxs[k]; }

    for (int off = 128; off >= 1; off >>= 1) {
        __syncthreads();
        if (tid < off) {
            float ov[8]; int oi[8];
            int pa = 0, pb = 0;
            #pragma unroll
            for (int k = 0; k < 8; ++k) {
                float va = svals[tid][pa];        int ia = sidx[tid][pa];
                float vb = svals[tid + off][pb];  int ib = sidx[tid + off][pb];
                bool ta = (va > vb) || ((va == vb) && (ia < ib));
                ov[k] = ta ? va : vb;
                oi[k] = ta ? ia : ib;
                pa += ta ? 1 : 0;
                pb += ta ? 0 : 1;
            }
            #pragma unroll
            for (int k = 0; k < 8; ++k) { svals[tid][k] = ov[k]; sidx[tid][k] = oi[k]; }
        }
    }
    __syncthreads();

    if (tid == 0) {
        float num = 0.0f, den = 0.0f;
        #pragma unroll
        for (int k = 0; k < 8; ++k) {
            float v = svals[0][k];
            int   c = consequents[sidx[0][k]];
            num += v * s1s[c];
            den += v * s0s[c];
        }
        out[b] = num / (den + EPSF);
    }
}

extern "C" void kernel_launch(void* const* d_in, const int* in_sizes, int n_in,
                              void* d_out, int out_size, void* d_ws, size_t ws_size,
                              hipStream_t stream) {
    const float* x      = (const float*)d_in[0];
    const int*   ant    = (const int*)d_in[1];
    const int*   cons   = (const int*)d_in[2];
    const float* in_c   = (const float*)d_in[3];
    const float* in_w   = (const float*)d_in[4];
    const float* out_c  = (const float*)d_in[5];
    const float* out_w  = (const float*)d_in[6];
    float*       out    = (float*)d_out;

    const int B = in_sizes[0] / DD;
    const int R = in_sizes[1] / DD;

    const bool shape_ok = (R == THREADS * 4 * ITERS) && (B % ROWS == 0);
    const size_t need = (size_t)R * 4;    // packed words only

    if (shape_ok && d_ws && ws_size >= need) {
        unsigned* g_off = (unsigned*)d_ws;
        pack_kernel<<<(R + 255) / 256, 256, 0, stream>>>(ant, g_off, R);
        anfis_fused8<<<B / ROWS, THREADS, 0, stream>>>(x, g_off, cons, in_c, in_w,
                                                       out_c, out_w, out);
    } else {
        anfis_kernel<<<B, 256, 0, stream>>>(x, ant, cons, in_c, in_w,
                                            out_c, out_w, out, R);
    }
}

// Round 19
// 32.882 us; speedup vs baseline: 1.0372x; 1.0372x over previous
//
#include <hip/hip_runtime.h>
#include <math.h>

#define DD 8
#define MM 7
#define MOO 9
#define NPTS 100
#define EPSF 1e-5f

#define THREADS 1024
#define ITERS 8           // uint4 code loads per thread; THREADS*4*ITERS == 32768
#define ROWS 8            // batch rows per block
#define CAP 256           // candidate buffer capacity per row
// Truncated-bf16 one-sided bounds: f~ >= 0.992203*f, trunc(max f~) >= 0.988326*f.
#define THR_SLACK 0.9879f

typedef unsigned uint32x4 __attribute__((ext_vector_type(4)));

__device__ __forceinline__ float bl(unsigned u) { return __uint_as_float(u << 16); }
__device__ __forceinline__ float bh(unsigned u) { return __uint_as_float(u & 0xFFFF0000u); }
__device__ __forceinline__ unsigned pkb(float a, float b) {
    return (__float_as_uint(b) & 0xFFFF0000u) | (__float_as_uint(a) >> 16);
}

// ---------------- pack: antecedents -> entry-index word ---------------------
// w & 0xFFFF = entry index into quad table 0 (0..4095)
// w >> 16    = entry index into quad table 1 (4096..8191, base pre-added)
__global__ __launch_bounds__(256) void pack_kernel(const int* __restrict__ ant,
                                                   unsigned* __restrict__ g_off,
                                                   int R) {
    int r = blockIdx.x * 256 + threadIdx.x;
    if (r < R) {
        const int4* a = reinterpret_cast<const int4*>(ant) + (size_t)r * 2;
        int4 lo = a[0], hi = a[1];
        int v[8] = {lo.x, lo.y, lo.z, lo.w, hi.x, hi.y, hi.z, hi.w};
        unsigned code = 0u;
        #pragma unroll
        for (int i = 0; i < 8; ++i) {
            int c = v[i];
            c = (c < 0) ? 7 : (c > MM - 1 ? MM - 1 : c);   // -1 -> wildcard slot 7
            code |= (unsigned)c << (3 * i);
        }
        g_off[r] = (code & 4095u) | (((code >> 12) + 4096u) << 16);
    }
}

// =================== fused kernel: 8 rows/block, scan + select ==============
// R15 configuration (empirical best, 32.8us): forced-MLP phase 3 -- inline-asm
// ds_read_b128 with "=v" outputs (compiler cannot sink opaque asm defs; C++
// ILP was re-sunk at VGPR=32 in R6-R10) -> 16 outstanding LDS reads per
// 8-rule batch, one lgkmcnt(0) per batch. sched_barrier(0) walls per guide
// rule #18. Counted-lgkmcnt pipelining (R16) and i16-log consume (R18) were
// both null-to-negative -- this is the confirmed-best interior.
__global__ __launch_bounds__(THREADS, 4) void anfis_fused8(
    const float* __restrict__ x,
    const unsigned* __restrict__ stream_off,
    const int* __restrict__ consequents,
    const float* __restrict__ in_centers,   // [D][M]
    const float* __restrict__ in_widths,    // [D][M]
    const float* __restrict__ out_centers,  // [MO]
    const float* __restrict__ out_widths,   // [MO]
    float* __restrict__ out)
{
    __shared__ uint4 quads[8192];        // 128 KB; aliased after phase 3:
                                         //   bytes [0,16K):  ushort wl[8192]
                                         //   bytes [16K,24K): float cvals[8][256]
                                         //   bytes [24K,32K): int   cidx[8][256]
    __shared__ float mu[ROWS][64];       // 2 KB
    __shared__ float pairs[ROWS][256];   // 8 KB exact f32 pair products
    __shared__ uint4 smaxpk[THREADS];    // 16 KB packed thread maxes
    __shared__ float s0s[MOO], s1s[MOO];
    __shared__ float sT[ROWS];
    __shared__ int   scnt[ROWS];
    __shared__ int   wlcnt;
    __shared__ float wv[ROWS][8];
    __shared__ int   wc[ROWS][8];

    const int tid = threadIdx.x;
    const int b0  = blockIdx.x * ROWS;

    unsigned short* wl = (unsigned short*)quads;          // 16 KB
    float* cvals = (float*)(quads + 1024);                // 8 KB  @16K
    int*   cidx  = (int*)(quads + 1536);                  // 8 KB  @24K

    // --- phase 0: membership tables (8 rows) + init ---
    if (tid < 512) {
        int row = tid >> 6, d = (tid >> 3) & 7, c = tid & 7;
        float v = 1.0f;
        if (c < MM) {
            float z = (x[(b0 + row) * DD + d] - in_centers[d * MM + c]) / in_widths[d * MM + c];
            v = expf(-0.5f * z * z);
            v = fminf(v, 1.0f);
            v = fmaxf(v, EPSF);
        }
        mu[row][(d << 3) + c] = v;
    } else if (tid >= 544 && tid < 544 + ROWS) {
        scnt[tid - 544] = 0;
    } else if (tid == 560) {
        wlcnt = 0;
    }
    __syncthreads();

    // --- phase 1: exact pair products (2048 entries, 2/thread) ---
    #pragma unroll
    for (int i = 0; i < 2; ++i) {
        int k = tid + i * THREADS;
        int row = k >> 8, e = k & 255;
        int p = e >> 6, q = e & 63;
        pairs[row][e] = mu[row][(2 * p) * 8 + (q & 7)] * mu[row][(2 * p + 1) * 8 + (q >> 3)];
    }
    __syncthreads();

    // --- phase 2: quad tables, bf16 x 8 rows per 16B entry, A-side hoisted ---
    #pragma unroll
    for (int h = 0; h < 2; ++h) {
        float a8[ROWS];
        const int ia = h * 128 + (tid & 63);
        #pragma unroll
        for (int r = 0; r < ROWS; ++r) a8[r] = pairs[r][ia];
        #pragma unroll
        for (int ii = 0; ii < 4; ++ii) {
            int k = tid + (h * 4 + ii) * THREADS;
            int ib = h * 128 + 64 + ((((tid >> 6) + 16 * ii)) & 63);
            float q0 = a8[0] * pairs[0][ib];
            float q1 = a8[1] * pairs[1][ib];
            float q2 = a8[2] * pairs[2][ib];
            float q3 = a8[3] * pairs[3][ib];
            float q4 = a8[4] * pairs[4][ib];
            float q5 = a8[5] * pairs[5][ib];
            float q6 = a8[6] * pairs[6][ib];
            float q7 = a8[7] * pairs[7][ib];
            quads[k] = make_uint4(pkb(q0, q1), pkb(q2, q3), pkb(q4, q5), pkb(q6, q7));
        }
    }
    __syncthreads();

    // --- phase 3: scan; 8-rule batches of 16 asm ds_read_b128 (forced MLP) ---
    const uint4* pk4 = reinterpret_cast<const uint4*>(stream_off);
    const unsigned qbase = (unsigned)(uintptr_t)&quads[0];
    float m[ROWS];
    #pragma unroll
    for (int r = 0; r < ROWS; ++r) m[r] = -1.0f;
    #pragma unroll
    for (int half = 0; half < 4; ++half) {
        uint4 cA = pk4[(2 * half) * THREADS + tid];
        uint4 cB = pk4[(2 * half + 1) * THREADS + tid];
        unsigned w[8] = {cA.x, cA.y, cA.z, cA.w, cB.x, cB.y, cB.z, cB.w};
        uint32x4 eA[8], eB[8];
        #pragma unroll
        for (int s = 0; s < 8; ++s) {
            unsigned alo = qbase + ((w[s] & 0xFFFFu) << 4);
            unsigned ahi = qbase + ((w[s] >> 16) << 4);
            asm volatile("ds_read_b128 %0, %1" : "=v"(eA[s]) : "v"(alo));
            asm volatile("ds_read_b128 %0, %1" : "=v"(eB[s]) : "v"(ahi));
        }
        __builtin_amdgcn_sched_barrier(0);
        asm volatile("s_waitcnt lgkmcnt(0)" ::: "memory");
        __builtin_amdgcn_sched_barrier(0);
        #pragma unroll
        for (int s = 0; s < 8; ++s) {
            uint32x4 a = eA[s], b = eB[s];
            m[0] = fmaxf(m[0], bl(a[0]) * bl(b[0]));
            m[1] = fmaxf(m[1], bh(a[0]) * bh(b[0]));
            m[2] = fmaxf(m[2], bl(a[1]) * bl(b[1]));
            m[3] = fmaxf(m[3], bh(a[1]) * bh(b[1]));
            m[4] = fmaxf(m[4], bl(a[2]) * bl(b[2]));
            m[5] = fmaxf(m[5], bh(a[2]) * bh(b[2]));
            m[6] = fmaxf(m[6], bl(a[3]) * bl(b[3]));
            m[7] = fmaxf(m[7], bh(a[3]) * bh(b[3]));
        }
    }
    smaxpk[tid] = make_uint4(pkb(m[0], m[1]), pkb(m[2], m[3]),
                             pkb(m[4], m[5]), pkb(m[6], m[7]));
    __syncthreads();          // quads DEAD from here on

    // --- phase 4: waves 0-7 extract thresholds; wave 8 does defuzz consts ---
    if (tid < 512) {
        int row = tid >> 6, lane = tid & 63;
        float mm[16];
        #pragma unroll
        for (int k = 0; k < 16; ++k) {
            uint4 e = smaxpk[lane + 64 * k];
            unsigned word = (row & 4) ? ((row & 2) ? e.w : e.z)
                                      : ((row & 2) ? e.y : e.x);
            mm[k] = (row & 1) ? bh(word) : bl(word);
        }
        float thr = -1.0f;
        #pragma unroll
        for (int round = 0; round < 8; ++round) {
            float lm = mm[0];
            #pragma unroll
            for (int k = 1; k < 16; ++k) lm = fmaxf(lm, mm[k]);
            float wm = lm;
            #pragma unroll
            for (int off = 32; off >= 1; off >>= 1)
                wm = fmaxf(wm, __shfl_xor(wm, off, 64));
            unsigned long long bal = __ballot(lm == wm);
            int first = (int)__ffsll(bal) - 1;
            if (lane == first) {                // remove exactly one instance
                bool done = false;
                #pragma unroll
                for (int k = 0; k < 16; ++k) {
                    bool rm = (!done) && (mm[k] == wm);
                    mm[k] = rm ? -2.0f : mm[k];
                    done = done || rm;
                }
            }
            thr = wm;
        }
        if (lane == 0) sT[row] = thr;
    } else if (tid < 512 + MOO) {
        int mo = tid - 512;
        float oc = out_centers[mo], ow = out_widths[mo];
        float s0 = 0.0f, s1 = 0.0f;
        for (int p = 0; p < NPTS; ++p) {
            float u = (float)p * (1.0f / 99.0f);
            float z = (u - oc) / ow;
            float e = expf(-0.5f * z * z);
            s0 += e;
            s1 += u * e;
        }
        s0s[mo] = s0;
        s1s[mo] = s1;
    }
    __syncthreads();

    // --- phase 5: build compacted worklist from register maxes ---
    {
        #pragma unroll
        for (int row = 0; row < ROWS; ++row) {
            if (m[row] >= THR_SLACK * sT[row]) {
                int pos = atomicAdd(&wlcnt, 1);
                wl[pos] = (unsigned short)((row << 10) | tid);   // max 8192 items
            }
        }
    }
    __syncthreads();

    // --- phase 6: half-wave per item; lane = one of the thread's 32 rules ---
    {
        const int hl = tid & 31;                   // rule slot within item
        const int j = hl >> 2, s = hl & 3;
        const int n = wlcnt;
        for (int i = (tid >> 5); i < n; i += 32) {
            int it  = wl[i];
            int row = it >> 10;
            int t   = it & 1023;
            int flat = (j * THREADS + t) * 4 + s;
            unsigned w = stream_off[flat];
            unsigned lo12 = w & 0xFFFFu;
            unsigned hi12 = (w >> 16) - 4096u;
            const float* P = pairs[row];
            float f = (P[lo12 & 63u] * P[64 + (lo12 >> 6)])
                    * (P[128 + (hi12 & 63u)] * P[192 + (hi12 >> 6)]);
            if (f >= sT[row]) {
                int pos = atomicAdd(&scnt[row], 1);
                if (pos < CAP) {
                    cvals[row * CAP + pos] = f;
                    cidx[row * CAP + pos]  = flat;
                }
            }
        }
    }
    __syncthreads();

    // --- phase 7: exact rank selection per row (val desc, orig idx asc) ---
    if (tid < 512) {
        int row = tid >> 6, lane = tid & 63;
        int n = scnt[row] < CAP ? scnt[row] : CAP;
        for (int c = lane; c < n; c += 64) {
            float v  = cvals[row * CAP + c];
            int   id = cidx[row * CAP + c];
            int rk = 0;
            for (int mI = 0; mI < n; ++mI) {
                float vm = cvals[row * CAP + mI];
                int   im = cidx[row * CAP + mI];
                rk += ((vm > v) || (vm == v && im < id)) ? 1 : 0;
            }
            if (rk < 8) {
                wv[row][rk] = v;
                wc[row][rk] = consequents[id];
            }
        }
    }
    __syncthreads();

    // --- phase 8: defuzzify ---
    if (tid < ROWS) {
        int row = tid;
        float num = 0.0f, den = 0.0f;
        #pragma unroll
        for (int k = 0; k < 8; ++k) {
            num += wv[row][k] * s1s[wc[row][k]];
            den += wv[row][k] * s0s[wc[row][k]];
        }
        out[b0 + row] = num / (den + EPSF);
    }
}

// ---------------- generic fallback (round-1 kernel, inline pack) ------------
__global__ __launch_bounds__(256) void anfis_kernel(
    const float* __restrict__ x,
    const int* __restrict__ ant,
    const int* __restrict__ consequents,
    const float* __restrict__ in_centers,
    const float* __restrict__ in_widths,
    const float* __restrict__ out_centers,
    const float* __restrict__ out_widths,
    float* __restrict__ out,
    int R)
{
    __shared__ float mu[64];
    __shared__ float pairs[256];
    __shared__ float s0s[MOO], s1s[MOO];
    __shared__ float svals[256][9];
    __shared__ int   sidx[256][9];

    const int tid = threadIdx.x;
    const int b   = blockIdx.x;

    if (tid < 64) {
        int d = tid >> 3, c = tid & 7;
        float v = 1.0f;
        if (c < MM) {
            float z = (x[b * DD + d] - in_centers[d * MM + c]) / in_widths[d * MM + c];
            v = expf(-0.5f * z * z);
            v = fminf(v, 1.0f);
            v = fmaxf(v, EPSF);
        }
        mu[tid] = v;
    } else if (tid < 64 + MOO) {
        int mo = tid - 64;
        float oc = out_centers[mo], ow = out_widths[mo];
        float s0 = 0.0f, s1 = 0.0f;
        for (int p = 0; p < NPTS; ++p) {
            float u = (float)p * (1.0f / 99.0f);
            float z = (u - oc) / ow;
            float e = expf(-0.5f * z * z);
            s0 += e;
            s1 += u * e;
        }
        s0s[mo] = s0;
        s1s[mo] = s1;
    }
    __syncthreads();

    {
        int p = tid >> 6, q = tid & 63;
        pairs[tid] = mu[(2 * p) * 8 + (q & 7)] * mu[(2 * p + 1) * 8 + (q >> 3)];
    }
    __syncthreads();

    float vals[8];
    int   idxs[8];
    #pragma unroll
    for (int k = 0; k < 8; ++k) { vals[k] = -1.0f; idxs[k] = 0x7fffffff; }

    for (int r = tid; r < R; r += 256) {
        const int4* a = reinterpret_cast<const int4*>(ant) + (size_t)r * 2;
        int4 lo = a[0], hi = a[1];
        int v[8] = {lo.x, lo.y, lo.z, lo.w, hi.x, hi.y, hi.z, hi.w};
        unsigned code = 0u;
        #pragma unroll
        for (int i = 0; i < 8; ++i) {
            int c = v[i];
            c = (c < 0) ? 7 : (c > MM - 1 ? MM - 1 : c);
            code |= (unsigned)c << (3 * i);
        }
        float f = pairs[code & 63]
                * pairs[64  + ((code >> 6)  & 63)]
                * pairs[128 + ((code >> 12) & 63)]
                * pairs[192 + ((code >> 18) & 63)];
        if (f > vals[7]) {
            float nv = f; int ni = r;
            #pragma unroll
            for (int k = 0; k < 8; ++k) {
                bool take = nv > vals[k];
                float cv = vals[k]; int ci = idxs[k];
                vals[k] = take ? nv : cv;
                idxs[k] = take ? ni : ci;
                nv = take ? cv : nv;
                ni = take ? ci : ni;
            }
        }
    }

    #pragma unroll
    for (int k = 0; k < 8; ++k) { svals[tid][k] = vals[k]; sidx[tid][k] = idxs[k]; }

    for (int off = 128; off >= 1; off >>= 1) {
        __syncthreads();
        if (tid < off) {
            float ov[8]; int oi[8];
            int pa = 0, pb = 0;
            #pragma unroll
            for (int k = 0; k < 8; ++k) {
                float va = svals[tid][pa];        int ia = sidx[tid][pa];
                float vb = svals[tid + off][pb];  int ib = sidx[tid + off][pb];
                bool ta = (va > vb) || ((va == vb) && (ia < ib));
                ov[k] = ta ? va : vb;
                oi[k] = ta ? ia : ib;
                pa += ta ? 1 : 0;
                pb += ta ? 0 : 1;
            }
            #pragma unroll
            for (int k = 0; k < 8; ++k) { svals[tid][k] = ov[k]; sidx[tid][k] = oi[k]; }
        }
    }
    __syncthreads();

    if (tid == 0) {
        float num = 0.0f, den = 0.0f;
        #pragma unroll
        for (int k = 0; k < 8; ++k) {
            float v = svals[0][k];
            int   c = consequents[sidx[0][k]];
            num += v * s1s[c];
            den += v * s0s[c];
        }
        out[b] = num / (den + EPSF);
    }
}

extern "C" void kernel_launch(void* const* d_in, const int* in_sizes, int n_in,
                              void* d_out, int out_size, void* d_ws, size_t ws_size,
                              hipStream_t stream) {
    const float* x      = (const float*)d_in[0];
    const int*   ant    = (const int*)d_in[1];
    const int*   cons   = (const int*)d_in[2];
    const float* in_c   = (const float*)d_in[3];
    const float* in_w   = (const float*)d_in[4];
    const float* out_c  = (const float*)d_in[5];
    const float* out_w  = (const float*)d_in[6];
    float*       out    = (float*)d_out;

    const int B = in_sizes[0] / DD;
    const int R = in_sizes[1] / DD;

    const bool shape_ok = (R == THREADS * 4 * ITERS) && (B % ROWS == 0);
    const size_t need = (size_t)R * 4;    // packed words only

    if (shape_ok && d_ws && ws_size >= need) {
        unsigned* g_off = (unsigned*)d_ws;
        pack_kernel<<<(R + 255) / 256, 256, 0, stream>>>(ant, g_off, R);
        anfis_fused8<<<B / ROWS, THREADS, 0, stream>>>(x, g_off, cons, in_c, in_w,
                                                       out_c, out_w, out);
    } else {
        anfis_kernel<<<B, 256, 0, stream>>>(x, ant, cons, in_c, in_w,
                                            out_c, out_w, out, R);
    }
}